// Round 4
// baseline (78.790 us; speedup 1.0000x reference)
//
#include <hip/hip_runtime.h>
#include <stdint.h>

#define B_   8
#define S_   2048
#define HID_ 512
#define M_   (B_ * S_)   // 16384
#define AW_  5

typedef __attribute__((ext_vector_type(8))) short bf16x8;
typedef __attribute__((ext_vector_type(4))) float f32x4;
typedef unsigned short u16;

__device__ __forceinline__ u16 f2bf(float f) {
    uint32_t u = __builtin_bit_cast(uint32_t, f);
    u += 0x7FFFu + ((u >> 16) & 1u);   // RNE
    return (u16)(u >> 16);
}
__device__ __forceinline__ float bf2f(u16 h) {
    uint32_t u = ((uint32_t)h) << 16;
    return __builtin_bit_cast(float, u);
}

// async global->LDS, 16B/lane (dest = wave-uniform base + lane*16, linear)
__device__ __forceinline__ void gload16(const void* g, void* l) {
    __builtin_amdgcn_global_load_lds(
        (const __attribute__((address_space(1))) void*)(uintptr_t)g,
        (__attribute__((address_space(3))) void*)(uint32_t)(uintptr_t)l,
        16, 0, 0);
}

// ---------------------------------------------------------------------------
// two W[k][n] f32 -> Wt[n][k] bf16 transposes (z selects)
// ---------------------------------------------------------------------------
__global__ __launch_bounds__(256) void trans2w(const float* __restrict__ S0,
                                               const float* __restrict__ S1,
                                               u16* __restrict__ D0,
                                               u16* __restrict__ D1) {
    const float* src = blockIdx.z ? S1 : S0;
    u16* dst = blockIdx.z ? D1 : D0;
    __shared__ float tile[32][33];
    const int k0 = blockIdx.y * 32, n0 = blockIdx.x * 32;
    const int tr = threadIdx.x >> 5, tc = threadIdx.x & 31;
#pragma unroll
    for (int p = 0; p < 4; ++p)
        tile[tr + p * 8][tc] = src[(long)(k0 + tr + p * 8) * HID_ + n0 + tc];
    __syncthreads();
#pragma unroll
    for (int p = 0; p < 4; ++p)
        dst[(long)(n0 + tr + p * 8) * HID_ + k0 + tc] = f2bf(tile[tc][tr + p * 8]);
}

// ---------------------------------------------------------------------------
// gemm1: h = relu(x @ W1 + b1), A is f32 (conversion fused via reg-staging).
// 128x128 tile, BK=64, dbuf LDS, T2 XOR-swizzle, XCD block swizzle.
// ---------------------------------------------------------------------------
__global__ __launch_bounds__(256, 2) void gemm1_f32a(const float* __restrict__ A,
                                                     const u16* __restrict__ Bt,
                                                     const float* __restrict__ bias,
                                                     u16* __restrict__ C) {
    __shared__ __attribute__((aligned(16))) u16 As[2][128 * 64];  // 16KB x2
    __shared__ __attribute__((aligned(16))) u16 Bs[2][128 * 64];

    const int tid = threadIdx.x;
    const int bid = blockIdx.x;
    const int swz = (bid & 7) * 64 + (bid >> 3);   // 512 blocks, bijective
    const int  bn   = (swz & 3) * 128;
    const long brow = (long)(swz >> 2) * 128;

    const int w  = tid >> 6;
    const int l  = tid & 63;
    const int wm = (w >> 1) * 64;
    const int wn = (w & 1) * 64;
    const int lr  = l & 15;
    const int lkb = (l >> 4) * 16;
    const int sw  = (lr & 7) << 4;

    // A reg-staging: seg0 = tid (rows 0..63), seg1 = tid+256 (rows 64..127)
    const int r0 = tid >> 2;
    const int c0 = (tid & 3) * 16;       // k-elem base
    const int r1 = 64 + r0;
    const float* ga0 = A + (brow + r0) * 512 + c0;
    const float* ga1 = A + (brow + r1) * 512 + c0;
    char* lw = (char*)&As[0][0];
    const int wb00 = r0 * 128 + ((c0 * 2 +  0) ^ ((r0 & 7) << 4));
    const int wb01 = r0 * 128 + ((c0 * 2 + 16) ^ ((r0 & 7) << 4));
    const int wb10 = r1 * 128 + ((c0 * 2 +  0) ^ ((r1 & 7) << 4));
    const int wb11 = r1 * 128 + ((c0 * 2 + 16) ^ ((r1 & 7) << 4));

    // B staging via global_load_lds (linear dest, inverse-swizzled source)
    int pq[4];
    const u16* srcB[4];
#pragma unroll
    for (int q = 0; q < 4; ++q) {
        const int p   = tid * 16 + q * 4096;
        const int row = p >> 7;
        const int cb  = (p & 127) ^ ((row & 7) << 4);
        pq[q]   = p;
        srcB[q] = Bt + (long)(bn + row) * 512 + (cb >> 1);
    }

    f32x4 acc[4][4];
#pragma unroll
    for (int i = 0; i < 4; ++i)
#pragma unroll
        for (int j = 0; j < 4; ++j) {
            f32x4 z = {0.f, 0.f, 0.f, 0.f};
            acc[i][j] = z;
        }

    float4 ra[4], rb[4];   // in-flight A f32 (seg0, seg1)

#define LOADA(k0)                                                        \
    {                                                                    \
        _Pragma("unroll") for (int u = 0; u < 4; ++u) {                  \
            ra[u] = *(const float4*)(ga0 + (k0) + u * 4);                \
            rb[u] = *(const float4*)(ga1 + (k0) + u * 4);                \
        }                                                                \
    }
#define CVTWRITE(buf)                                                    \
    {                                                                    \
        union { u16 u[8]; int4 v; } q0, q1, q2, q3;                      \
        q0.u[0]=f2bf(ra[0].x); q0.u[1]=f2bf(ra[0].y); q0.u[2]=f2bf(ra[0].z); q0.u[3]=f2bf(ra[0].w); \
        q0.u[4]=f2bf(ra[1].x); q0.u[5]=f2bf(ra[1].y); q0.u[6]=f2bf(ra[1].z); q0.u[7]=f2bf(ra[1].w); \
        q1.u[0]=f2bf(ra[2].x); q1.u[1]=f2bf(ra[2].y); q1.u[2]=f2bf(ra[2].z); q1.u[3]=f2bf(ra[2].w); \
        q1.u[4]=f2bf(ra[3].x); q1.u[5]=f2bf(ra[3].y); q1.u[6]=f2bf(ra[3].z); q1.u[7]=f2bf(ra[3].w); \
        q2.u[0]=f2bf(rb[0].x); q2.u[1]=f2bf(rb[0].y); q2.u[2]=f2bf(rb[0].z); q2.u[3]=f2bf(rb[0].w); \
        q2.u[4]=f2bf(rb[1].x); q2.u[5]=f2bf(rb[1].y); q2.u[6]=f2bf(rb[1].z); q2.u[7]=f2bf(rb[1].w); \
        q3.u[0]=f2bf(rb[2].x); q3.u[1]=f2bf(rb[2].y); q3.u[2]=f2bf(rb[2].z); q3.u[3]=f2bf(rb[2].w); \
        q3.u[4]=f2bf(rb[3].x); q3.u[5]=f2bf(rb[3].y); q3.u[6]=f2bf(rb[3].z); q3.u[7]=f2bf(rb[3].w); \
        *(int4*)(lw + (buf) * 16384 + wb00) = q0.v;                      \
        *(int4*)(lw + (buf) * 16384 + wb01) = q1.v;                      \
        *(int4*)(lw + (buf) * 16384 + wb10) = q2.v;                      \
        *(int4*)(lw + (buf) * 16384 + wb11) = q3.v;                      \
    }
#define STAGEB(buf, k0)                                                  \
    {                                                                    \
        _Pragma("unroll") for (int q = 0; q < 4; ++q)                    \
            gload16(srcB[q] + (k0), (char*)&Bs[buf][0] + pq[q]);         \
    }

    // prologue: tile 0
    LOADA(0);
    STAGEB(0, 0);
    CVTWRITE(0);
    __syncthreads();

    int cur = 0;
    for (int t = 0; t < 8; ++t) {
        if (t < 7) {
            LOADA((t + 1) * 64);             // A f32 loads issued first
            STAGEB(cur ^ 1, (t + 1) * 64);   // B async gloads after
        }
#pragma unroll
        for (int kk = 0; kk < 2; ++kk) {
            bf16x8 af[4], bfr[4];
#pragma unroll
            for (int i = 0; i < 4; ++i) {
                const int off = (wm + i * 16 + lr) * 128 + ((kk * 64 + lkb) ^ sw);
                af[i] = *(const bf16x8*)((const char*)&As[cur][0] + off);
            }
#pragma unroll
            for (int j = 0; j < 4; ++j) {
                const int off = (wn + j * 16 + lr) * 128 + ((kk * 64 + lkb) ^ sw);
                bfr[j] = *(const bf16x8*)((const char*)&Bs[cur][0] + off);
            }
#pragma unroll
            for (int i = 0; i < 4; ++i)
#pragma unroll
                for (int j = 0; j < 4; ++j)
                    acc[i][j] = __builtin_amdgcn_mfma_f32_16x16x32_bf16(
                        af[i], bfr[j], acc[i][j], 0, 0, 0);
        }
        if (t < 7) CVTWRITE(cur ^ 1);        // waits A-loads (vmcnt), writes other buf
        __syncthreads();
        cur ^= 1;
    }
#undef LOADA
#undef CVTWRITE
#undef STAGEB

    float bv[4];
#pragma unroll
    for (int j = 0; j < 4; ++j) bv[j] = bias[bn + wn + j * 16 + lr];
    const int rq = (l >> 4) * 4;
#pragma unroll
    for (int i = 0; i < 4; ++i)
#pragma unroll
        for (int q = 0; q < 4; ++q) {
            const long row = brow + wm + i * 16 + rq + q;
            u16* crow = C + row * 512 + bn + wn + lr;
#pragma unroll
            for (int j = 0; j < 4; ++j)
                crow[j * 16] = f2bf(fmaxf(acc[i][j][q] + bv[j], 0.f));
        }
}

// ---------------------------------------------------------------------------
// plain bf16 GEMM (gemm3): C = A @ Bt^T, both bf16. Same structure as r3.
// ---------------------------------------------------------------------------
__global__ __launch_bounds__(256, 2) void gemm_bf16(const u16* __restrict__ A,
                                                    const u16* __restrict__ Bt,
                                                    u16* __restrict__ C) {
    __shared__ __attribute__((aligned(16))) u16 As[2][128 * 64];
    __shared__ __attribute__((aligned(16))) u16 Bs[2][128 * 64];

    const int tid = threadIdx.x;
    const int bid = blockIdx.x;
    const int swz = (bid & 7) * 64 + (bid >> 3);
    const int  bn   = (swz & 3) * 128;
    const long brow = (long)(swz >> 2) * 128;

    const int w  = tid >> 6;
    const int l  = tid & 63;
    const int wm = (w >> 1) * 64;
    const int wn = (w & 1) * 64;
    const int lr  = l & 15;
    const int lkb = (l >> 4) * 16;
    const int sw  = (lr & 7) << 4;

    int pq[4];
    const u16* srcA[4];
    const u16* srcB[4];
#pragma unroll
    for (int q = 0; q < 4; ++q) {
        const int p   = tid * 16 + q * 4096;
        const int row = p >> 7;
        const int cb  = (p & 127) ^ ((row & 7) << 4);
        pq[q]   = p;
        srcA[q] = A  + (brow + row) * 512 + (cb >> 1);
        srcB[q] = Bt + (long)(bn + row) * 512 + (cb >> 1);
    }

    f32x4 acc[4][4];
#pragma unroll
    for (int i = 0; i < 4; ++i)
#pragma unroll
        for (int j = 0; j < 4; ++j) {
            f32x4 z = {0.f, 0.f, 0.f, 0.f};
            acc[i][j] = z;
        }

#define STAGE(buf, k0)                                                   \
    {                                                                    \
        _Pragma("unroll") for (int q = 0; q < 4; ++q) {                  \
            gload16(srcA[q] + (k0), (char*)&As[buf][0] + pq[q]);         \
            gload16(srcB[q] + (k0), (char*)&Bs[buf][0] + pq[q]);         \
        }                                                                \
    }

    int cur = 0;
    STAGE(0, 0);
    __syncthreads();

    for (int t = 0; t < 8; ++t) {
        if (t < 7) STAGE(cur ^ 1, (t + 1) * 64);
#pragma unroll
        for (int kk = 0; kk < 2; ++kk) {
            bf16x8 af[4], bfr[4];
#pragma unroll
            for (int i = 0; i < 4; ++i) {
                const int off = (wm + i * 16 + lr) * 128 + ((kk * 64 + lkb) ^ sw);
                af[i] = *(const bf16x8*)((const char*)&As[cur][0] + off);
            }
#pragma unroll
            for (int j = 0; j < 4; ++j) {
                const int off = (wn + j * 16 + lr) * 128 + ((kk * 64 + lkb) ^ sw);
                bfr[j] = *(const bf16x8*)((const char*)&Bs[cur][0] + off);
            }
#pragma unroll
            for (int i = 0; i < 4; ++i)
#pragma unroll
                for (int j = 0; j < 4; ++j)
                    acc[i][j] = __builtin_amdgcn_mfma_f32_16x16x32_bf16(
                        af[i], bfr[j], acc[i][j], 0, 0, 0);
        }
        __syncthreads();
        cur ^= 1;
    }
#undef STAGE

    const int rq = (l >> 4) * 4;
#pragma unroll
    for (int i = 0; i < 4; ++i)
#pragma unroll
        for (int q = 0; q < 4; ++q) {
            const long row = brow + wm + i * 16 + rq + q;
            u16* crow = C + row * 512 + bn + wn + lr;
#pragma unroll
            for (int j = 0; j < 4; ++j)
                crow[j * 16] = f2bf(acc[i][j][q]);
        }
}

// ---------------------------------------------------------------------------
// gemm4 + FC fused: T = relu(aw @ W2 + b2) kept in regs; per-wave partial
// dot with Wfc (512x2) reduced via shfl_xor; 8 partial slots, no T write.
// ---------------------------------------------------------------------------
__global__ __launch_bounds__(256, 2) void gemm4_fc(const u16* __restrict__ A,
                                                   const u16* __restrict__ Bt,
                                                   const float* __restrict__ b2,
                                                   const float* __restrict__ Wfc,
                                                   float* __restrict__ partials) {
    __shared__ __attribute__((aligned(16))) u16 As[2][128 * 64];
    __shared__ __attribute__((aligned(16))) u16 Bs[2][128 * 64];

    const int tid = threadIdx.x;
    const int bid = blockIdx.x;
    const int swz = (bid & 7) * 64 + (bid >> 3);
    const int  bn   = (swz & 3) * 128;
    const long brow = (long)(swz >> 2) * 128;

    const int w  = tid >> 6;
    const int l  = tid & 63;
    const int wm = (w >> 1) * 64;
    const int wn = (w & 1) * 64;
    const int lr  = l & 15;
    const int lkb = (l >> 4) * 16;
    const int sw  = (lr & 7) << 4;

    int pq[4];
    const u16* srcA[4];
    const u16* srcB[4];
#pragma unroll
    for (int q = 0; q < 4; ++q) {
        const int p   = tid * 16 + q * 4096;
        const int row = p >> 7;
        const int cb  = (p & 127) ^ ((row & 7) << 4);
        pq[q]   = p;
        srcA[q] = A  + (brow + row) * 512 + (cb >> 1);
        srcB[q] = Bt + (long)(bn + row) * 512 + (cb >> 1);
    }

    f32x4 acc[4][4];
#pragma unroll
    for (int i = 0; i < 4; ++i)
#pragma unroll
        for (int j = 0; j < 4; ++j) {
            f32x4 z = {0.f, 0.f, 0.f, 0.f};
            acc[i][j] = z;
        }

#define STAGE(buf, k0)                                                   \
    {                                                                    \
        _Pragma("unroll") for (int q = 0; q < 4; ++q) {                  \
            gload16(srcA[q] + (k0), (char*)&As[buf][0] + pq[q]);         \
            gload16(srcB[q] + (k0), (char*)&Bs[buf][0] + pq[q]);         \
        }                                                                \
    }

    int cur = 0;
    STAGE(0, 0);
    __syncthreads();

    for (int t = 0; t < 8; ++t) {
        if (t < 7) STAGE(cur ^ 1, (t + 1) * 64);
#pragma unroll
        for (int kk = 0; kk < 2; ++kk) {
            bf16x8 af[4], bfr[4];
#pragma unroll
            for (int i = 0; i < 4; ++i) {
                const int off = (wm + i * 16 + lr) * 128 + ((kk * 64 + lkb) ^ sw);
                af[i] = *(const bf16x8*)((const char*)&As[cur][0] + off);
            }
#pragma unroll
            for (int j = 0; j < 4; ++j) {
                const int off = (wn + j * 16 + lr) * 128 + ((kk * 64 + lkb) ^ sw);
                bfr[j] = *(const bf16x8*)((const char*)&Bs[cur][0] + off);
            }
#pragma unroll
            for (int i = 0; i < 4; ++i)
#pragma unroll
                for (int j = 0; j < 4; ++j)
                    acc[i][j] = __builtin_amdgcn_mfma_f32_16x16x32_bf16(
                        af[i], bfr[j], acc[i][j], 0, 0, 0);
        }
        __syncthreads();
        cur ^= 1;
    }
#undef STAGE

    float bv[4], w0[4], w1[4];
#pragma unroll
    for (int j = 0; j < 4; ++j) {
        const int col = bn + wn + j * 16 + lr;
        bv[j] = b2[col];
        w0[j] = Wfc[2 * col];
        w1[j] = Wfc[2 * col + 1];
    }
    const int rq = (l >> 4) * 4;
    const int slot = (bn >> 7) * 2 + (wn >> 6);   // 0..7
#pragma unroll
    for (int i = 0; i < 4; ++i)
#pragma unroll
        for (int q = 0; q < 4; ++q) {
            float s0 = 0.f, s1 = 0.f;
#pragma unroll
            for (int j = 0; j < 4; ++j) {
                const float v = fmaxf(acc[i][j][q] + bv[j], 0.f);
                s0 += v * w0[j];
                s1 += v * w1[j];
            }
#pragma unroll
            for (int m = 1; m < 16; m <<= 1) {   // reduce over lr (16 lanes)
                s0 += __shfl_xor(s0, m);
                s1 += __shfl_xor(s1, m);
            }
            if (lr == 0) {
                const long row = brow + wm + i * 16 + rq + q;
                float* pp = partials + ((long)slot * M_ + row) * 2;
                pp[0] = s0;
                pp[1] = s1;
            }
        }
}

// ---------------------------------------------------------------------------
// aw = winsum11(g): bf16 in -> bf16 (for gemm4) AND f32 (final output 2)
// ---------------------------------------------------------------------------
__global__ __launch_bounds__(256) void winsum_f(const u16* __restrict__ g,
                                                u16* __restrict__ awb,
                                                float* __restrict__ awf) {
    const long idx = (long)blockIdx.x * 256 + threadIdx.x;
    const int  c8  = (int)(idx & 63);
    const long bs  = idx >> 6;
    const int  s   = (int)(bs & (S_ - 1));

    float acc[8] = {};
#pragma unroll
    for (int d = -AW_; d <= AW_; ++d) {
        const int ss = s + d;
        if (0 <= ss && ss < S_) {
            const int4 v = *(const int4*)&g[(bs + d) * HID_ + c8 * 8];
            const u16* u = (const u16*)&v;
#pragma unroll
            for (int e = 0; e < 8; ++e) acc[e] += bf2f(u[e]);
        }
    }
    union { u16 u[8]; int4 v; } r;
#pragma unroll
    for (int e = 0; e < 8; ++e) r.u[e] = f2bf(acc[e]);
    *(int4*)&awb[bs * HID_ + c8 * 8] = r.v;
    float4 o0 = {acc[0], acc[1], acc[2], acc[3]};
    float4 o1 = {acc[4], acc[5], acc[6], acc[7]};
    *(float4*)&awf[bs * HID_ + c8 * 8]     = o0;
    *(float4*)&awf[bs * HID_ + c8 * 8 + 4] = o1;
}

// ---------------------------------------------------------------------------
// out[row] = sum_8 partials + bfc
// ---------------------------------------------------------------------------
__global__ __launch_bounds__(256) void fc_reduce(const float* __restrict__ partials,
                                                 const float* __restrict__ bfc,
                                                 float* __restrict__ out) {
    const int row = blockIdx.x * 256 + threadIdx.x;
    float s0 = bfc[0], s1 = bfc[1];
#pragma unroll
    for (int p = 0; p < 8; ++p) {
        s0 += partials[((long)p * M_ + row) * 2 + 0];
        s1 += partials[((long)p * M_ + row) * 2 + 1];
    }
    out[row * 2 + 0] = s0;
    out[row * 2 + 1] = s1;
}

// ---------------------------------------------------------------------------
extern "C" void kernel_launch(void* const* d_in, const int* in_sizes, int n_in,
                              void* d_out, int out_size, void* d_ws, size_t ws_size,
                              hipStream_t stream) {
    const float* x   = (const float*)d_in[0];
    const float* W1  = (const float*)d_in[1];
    const float* b1  = (const float*)d_in[2];
    // d_in[3]=Wq, d_in[4]=Wk dead: softmax over singleton axis == 1.0
    const float* Wv  = (const float*)d_in[5];
    const float* W2  = (const float*)d_in[6];
    const float* b2  = (const float*)d_in[7];
    const float* Wfc = (const float*)d_in[8];
    const float* bfc = (const float*)d_in[9];

    float* out_part = (float*)d_out;                 // 16384*2 f32
    float* aw_f32   = (float*)d_out + (long)M_ * 2;  // 16384*512 f32 (32MB) "Q"

    // Q scratch until winsum_f overwrites it with the f32 aw output:
    u16* W1t = (u16*)aw_f32;            // 512KB, dead after gemm1
    u16* Wvt = W1t + 262144;            // 512KB, dead after gemm3

    // ws (>=32MB, proven r2):
    u16* h   = (u16*)d_ws;                         // [0,16M):  h, then awb
    u16* g   = (u16*)d_ws + 8388608;               // [16M,32M): g (dead after winsum)
    u16* awb = h;
    u16* W2t = g;                                  // 512KB in g's dead region
    float* partials = (float*)((char*)d_ws + 16 * 1024 * 1024 + 512 * 1024);  // 1MB

    trans2w<<<dim3(16, 16, 2), 256, 0, stream>>>(W1, Wv, W1t, Wvt);
    // 1) h = relu(x @ W1 + b1)           (f32->bf16 conversion fused)
    gemm1_f32a<<<512, 256, 0, stream>>>(x, W1t, b1, h);
    // 2) g = h @ Wv                      (winsum commutes with Wv)
    gemm_bf16<<<512, 256, 0, stream>>>(h, Wvt, g);
    // 3) aw = winsum11(g)  -> bf16 (ws) + f32 (output 2, fills Q)
    winsum_f<<<4096, 256, 0, stream>>>(g, awb, aw_f32);
    // 4) W2^T (into g's dead region, after winsum consumed g)
    trans2w<<<dim3(16, 16, 1), 256, 0, stream>>>(W2, W2, W2t, W2t);
    // 5) partial out = relu(aw @ W2 + b2) @ Wfc   (t never materialized)
    gemm4_fc<<<512, 256, 0, stream>>>(awb, W2t, b2, Wfc, partials);
    // 6) out = sum partials + bfc
    fc_reduce<<<64, 256, 0, stream>>>(partials, bfc, out_part);
}